// Round 6
// baseline (133.710 us; speedup 1.0000x reference)
//
#include <hip/hip_runtime.h>
#include <cstdint>

#define DMODEL 512
#define NH 8
#define DK 64
#define SS 2048
#define MTOT 8192

typedef unsigned short u16;
typedef __bf16 bf16_t;
typedef bf16_t bf16x8 __attribute__((ext_vector_type(8)));
typedef short s16x4 __attribute__((ext_vector_type(4)));
typedef float f32x4 __attribute__((ext_vector_type(4)));

// hardware exp2 (v_exp_f32)
__device__ __forceinline__ float exp2_hw(float x) {
  return __builtin_amdgcn_exp2f(x);
}

// hardware RNE f32->bf16
__device__ __forceinline__ u16 bfc(float f) {
  __bf16 h = (__bf16)f;
  return __builtin_bit_cast(u16, h);
}

__device__ __forceinline__ void gload_lds16(const void* g, void* l) {
  __builtin_amdgcn_global_load_lds(
      (const __attribute__((address_space(1))) unsigned int*)g,
      (__attribute__((address_space(3))) unsigned int*)l, 16, 0, 0);
}

// ---------------- fp32 -> bf16 conversion (inputs + weights) ----------------
__global__ __launch_bounds__(256) void convert_kernel(
    const float* __restrict__ Q, const float* __restrict__ K, const float* __restrict__ V,
    const float* __restrict__ Wq, const float* __restrict__ Wk,
    const float* __restrict__ Wv, const float* __restrict__ Wo,
    u16* __restrict__ Qb, u16* __restrict__ Kb, u16* __restrict__ Vb,
    u16* __restrict__ Wqb, u16* __restrict__ Wkb, u16* __restrict__ Wvb,
    u16* __restrict__ Wob)
{
  const int NBIG = MTOT * DMODEL;      // 4194304
  const int NW = DMODEL * DMODEL;      // 262144
  const int TOT4 = (3 * NBIG + 4 * NW) / 4;
  for (int i = blockIdx.x * blockDim.x + threadIdx.x; i < TOT4;
       i += gridDim.x * blockDim.x) {
    int e = i * 4;
    const float* src; u16* dst; int off;
    if (e < 3 * NBIG) {
      int w = e / NBIG; off = e - w * NBIG;
      src = (w == 0) ? Q : (w == 1) ? K : V;
      dst = (w == 0) ? Qb : (w == 1) ? Kb : Vb;
    } else {
      int e2 = e - 3 * NBIG; int w = e2 / NW; off = e2 - w * NW;
      src = (w == 0) ? Wq : (w == 1) ? Wk : (w == 2) ? Wv : Wo;
      dst = (w == 0) ? Wqb : (w == 1) ? Wkb : (w == 2) ? Wvb : Wob;
    }
    float4 v = *reinterpret_cast<const float4*>(src + off);
    uint64_t p = (uint64_t)bfc(v.x) | ((uint64_t)bfc(v.y) << 16) |
                 ((uint64_t)bfc(v.z) << 32) | ((uint64_t)bfc(v.w) << 48);
    *reinterpret_cast<uint64_t*>(dst + off) = p;
  }
}

// ---------------- 128x128 GEMM core: C = X @ W^T (both K-contiguous) --------
// 256 threads = 4 waves (2x2), each wave 64x64 (4x4 frags of 16x16x32 bf16)
// LDS tiles XOR-swizzled: 16B slot s of row r holds global slot s^(r&7).
__device__ __forceinline__ void gemm128_core(
    const u16* __restrict__ X, const u16* __restrict__ W,
    int bm, int bn, u16* As, u16* Bs, f32x4 (&acc)[4][4])
{
  const int tid = threadIdx.x;
  const int wid = tid >> 6, lane = tid & 63;
  const int wr = wid >> 1, wc = wid & 1;
  const int lrow = lane >> 3;
  const int lcolS = (((lane & 7) ^ lrow) * 8);   // pre-swizzled source column
  const int l15 = lane & 15, lg = lane >> 4;
  const u16* Ab = X + (int64_t)bm * 128 * DMODEL;
  const u16* Bb = W + (int64_t)bn * 128 * DMODEL;
  for (int k0 = 0; k0 < DMODEL; k0 += 64) {
    __syncthreads();
    #pragma unroll
    for (int j = 0; j < 4; ++j) {
      int c = wid * 4 + j;                    // chunk: rows c*8..c*8+7
      gload_lds16(Ab + (int64_t)(c * 8 + lrow) * DMODEL + k0 + lcolS, As + c * 512);
      gload_lds16(Bb + (int64_t)(c * 8 + lrow) * DMODEL + k0 + lcolS, Bs + c * 512);
    }
    asm volatile("s_waitcnt vmcnt(0)" ::: "memory");
    __syncthreads();
    #pragma unroll
    for (int kk = 0; kk < 2; ++kk) {
      bf16x8 af[4], bfr[4];
      #pragma unroll
      for (int i = 0; i < 4; ++i) {
        int rowA = wr * 64 + i * 16 + l15;
        int rowB = wc * 64 + i * 16 + l15;
        int slot = ((kk * 4 + lg) ^ (l15 & 7)) * 8;
        af[i]  = *reinterpret_cast<const bf16x8*>(As + rowA * 64 + slot);
        bfr[i] = *reinterpret_cast<const bf16x8*>(Bs + rowB * 64 + slot);
      }
      #pragma unroll
      for (int i = 0; i < 4; ++i)
        #pragma unroll
        for (int j = 0; j < 4; ++j)
          acc[i][j] = __builtin_amdgcn_mfma_f32_16x16x32_bf16(af[i], bfr[j], acc[i][j], 0, 0, 0);
    }
  }
}

// ---------------- QKV projection: out scattered to per-head layout ----------
// q,k: [B][H][S][DK] bf16 ; v: [B][H][DK][S] bf16 (pre-transposed for attn)
// K rows pre-scaled by (1/sqrt(dk))*log2(e) so attn exp2 needs no multiply.
#define C_QK 0.18033688011112043f   // (1/8) * log2(e)
__global__ __launch_bounds__(256) void qkv_gemm(
    const u16* __restrict__ Qb, const u16* __restrict__ Kb, const u16* __restrict__ Vb,
    const u16* __restrict__ Wqb, const u16* __restrict__ Wkb, const u16* __restrict__ Wvb,
    const float* __restrict__ bq, const float* __restrict__ bk, const float* __restrict__ bv,
    u16* __restrict__ qh, u16* __restrict__ kh, u16* __restrict__ vh)
{
  __shared__ u16 As[128 * 64], Bs[128 * 64];
  const int z = blockIdx.z;
  const u16* X = (z == 0) ? Qb : (z == 1) ? Kb : Vb;
  const u16* W = (z == 0) ? Wqb : (z == 1) ? Wkb : Wvb;
  const float* bias = (z == 0) ? bq : (z == 1) ? bk : bv;
  u16* out = (z == 0) ? qh : (z == 1) ? kh : vh;
  const float scale = (z == 1) ? C_QK : 1.0f;

  f32x4 acc[4][4] = {};
  gemm128_core(X, W, blockIdx.x, blockIdx.y, As, Bs, acc);

  const int lane = threadIdx.x & 63, wid = threadIdx.x >> 6;
  const int wr = wid >> 1, wc = wid & 1;
  #pragma unroll
  for (int j = 0; j < 4; ++j) {
    int n = blockIdx.y * 128 + wc * 64 + j * 16 + (lane & 15);
    float bv_ = bias[n];
    int h = n >> 6, d = n & 63;
    #pragma unroll
    for (int i = 0; i < 4; ++i) {
      int mbase = blockIdx.x * 128 + wr * 64 + i * 16 + (lane >> 4) * 4;
      #pragma unroll
      for (int r = 0; r < 4; ++r) {
        int m = mbase + r;
        int b = m >> 11, s = m & 2047;
        u16 val = bfc((acc[i][j][r] + bv_) * scale);
        if (z == 2)
          out[((int64_t)(b * NH + h) * DK + d) * SS + s] = val;
        else
          out[((int64_t)((b * NH + h) * SS + s) << 6) | d] = val;
      }
    }
  }
}

// ---------------- flash attention: 128 q-rows/block, KV tiles of 64 ---------
// Swapped QK^T (mfma(K,Q)) -> P^T fragments per-lane; packed cvt_pk P staged
// through per-wave LDS (b64 writes / b128 reads, XOR-swizzled); PV uses K=32
// mfma with full-slot b128 V^T reads (conflict-free pattern). 32 q-rows per
// wave: every K/V LDS fragment read feeds 2x MFMA. Fixed-max softmax.
__global__ __launch_bounds__(256) void attn_kernel(
    const u16* __restrict__ qh, const u16* __restrict__ kh, const u16* __restrict__ vh,
    u16* __restrict__ ctx)
{
  __shared__ u16 Ks[2][64 * 64];
  __shared__ u16 Vts[2][64 * 64];   // [d][k] (source pre-transposed in global)
  __shared__ u16 Ps[4][2][16 * 64]; // per-wave, per-q-half P tile [q][key]

  const int qt = blockIdx.x;        // 0..15, 128 q-rows per block
  const int bh = blockIdx.y;
  const int b = bh >> 3, h = bh & 7;
  const u16* Qp = qh + (int64_t)bh * SS * DK;
  const u16* Kp = kh + (int64_t)bh * SS * DK;
  const u16* Vp = vh + (int64_t)bh * SS * DK;  // [DK][SS] per head

  const int tid = threadIdx.x;
  const int wid = tid >> 6, lane = tid & 63;
  const int l15 = lane & 15, lg = lane >> 4;
  const int m7 = l15 & 7;
  const int lrow = lane >> 3;
  const int lcolS = (((lane & 7) ^ lrow) * 8);  // pre-swizzled source column

  // Q fragments: rows qt*128 + wid*32 + hh*16 + l15
  bf16x8 qf[2][2];
  #pragma unroll
  for (int hh = 0; hh < 2; ++hh) {
    const u16* qrow = Qp + (int64_t)(qt * 128 + wid * 32 + hh * 16 + l15) * DK + lg * 8;
    qf[hh][0] = *reinterpret_cast<const bf16x8*>(qrow);
    qf[hh][1] = *reinterpret_cast<const bf16x8*>(qrow + 32);
  }

  f32x4 oacc[2][4] = {};
  f32x4 lsumv[2] = {};
  u16* Pw = &Ps[wid][0][0];

  // prologue: stage tile 0 into buffer 0
  #pragma unroll
  for (int j = 0; j < 2; ++j) {
    int c = wid * 2 + j;
    gload_lds16(Kp + (int64_t)(c * 8 + lrow) * DK + lcolS, Ks[0] + c * 512);
    gload_lds16(Vp + (int64_t)(c * 8 + lrow) * SS + lcolS, Vts[0] + c * 512);
  }
  asm volatile("s_waitcnt vmcnt(0)" ::: "memory");
  __syncthreads();

  for (int kt = 0; kt < SS / 64; ++kt) {
    const int cur = kt & 1;
    if (kt + 1 < SS / 64) {
      #pragma unroll
      for (int j = 0; j < 2; ++j) {
        int c = wid * 2 + j;
        gload_lds16(Kp + (int64_t)((kt + 1) * 64 + c * 8 + lrow) * DK + lcolS,
                    Ks[cur ^ 1] + c * 512);
        gload_lds16(Vp + (int64_t)(c * 8 + lrow) * SS + (kt + 1) * 64 + lcolS,
                    Vts[cur ^ 1] + c * 512);
      }
    }

    // QK^T + softmax + pack P, per q-half
    #pragma unroll
    for (int hh = 0; hh < 2; ++hh) {
      f32x4 sacc[4] = {};
      #pragma unroll
      for (int ks = 0; ks < 2; ++ks) {
        #pragma unroll
        for (int nt = 0; nt < 4; ++nt) {
          int slot = ((ks * 4 + lg) ^ m7) * 8;
          bf16x8 kf = *reinterpret_cast<const bf16x8*>(
              Ks[cur] + (nt * 16 + l15) * 64 + slot);
          sacc[nt] = __builtin_amdgcn_mfma_f32_16x16x32_bf16(kf, qf[hh][ks], sacc[nt], 0, 0, 0);
        }
      }
      // fixed-max: P = 2^s (K pre-scaled); pack pairs, write 8B to Ps
      #pragma unroll
      for (int nt = 0; nt < 4; ++nt) {
        f32x4 p;
        #pragma unroll
        for (int r = 0; r < 4; ++r) p[r] = exp2_hw(sacc[nt][r]);
        lsumv[hh] += p;
        uint32_t lo = (uint32_t)bfc(p[0]) | ((uint32_t)bfc(p[1]) << 16);
        uint32_t hi = (uint32_t)bfc(p[2]) | ((uint32_t)bfc(p[3]) << 16);
        uint64_t pk2 = ((uint64_t)hi << 32) | lo;
        // row l15, keys nt*16+lg*4..+3 -> slot (2nt+(lg>>1))^m7, half lg&1
        *reinterpret_cast<uint64_t*>(
            Pw + hh * 1024 + l15 * 64 + (((2 * nt + (lg >> 1)) ^ m7) * 8) + (lg & 1) * 4) = pk2;
      }
    }

    // PV: O^T[d][q] += V^T[d][k] @ P^T[k][q], K=32 mfma; vt reused for both halves
    #pragma unroll
    for (int kg = 0; kg < 2; ++kg) {
      int slot = ((kg * 4 + lg) ^ m7) * 8;
      bf16x8 pb0 = *reinterpret_cast<const bf16x8*>(Pw + 0 * 1024 + l15 * 64 + slot);
      bf16x8 pb1 = *reinterpret_cast<const bf16x8*>(Pw + 1 * 1024 + l15 * 64 + slot);
      #pragma unroll
      for (int dt = 0; dt < 4; ++dt) {
        bf16x8 vt = *reinterpret_cast<const bf16x8*>(
            Vts[cur] + (dt * 16 + l15) * 64 + slot);
        oacc[0][dt] = __builtin_amdgcn_mfma_f32_16x16x32_bf16(vt, pb0, oacc[0][dt], 0, 0, 0);
        oacc[1][dt] = __builtin_amdgcn_mfma_f32_16x16x32_bf16(vt, pb1, oacc[1][dt], 0, 0, 0);
      }
    }

    // next buffer staged + everyone done reading cur
    asm volatile("s_waitcnt vmcnt(0)" ::: "memory");
    __syncthreads();
  }

  #pragma unroll
  for (int hh = 0; hh < 2; ++hh) {
    float lsum = lsumv[hh][0] + lsumv[hh][1] + lsumv[hh][2] + lsumv[hh][3];
    lsum += __shfl_xor(lsum, 16);
    lsum += __shfl_xor(lsum, 32);
    float rn = 1.f / lsum;
    const int q = qt * 128 + wid * 32 + hh * 16 + l15;
    u16* crow = ctx + (int64_t)(b * SS + q) * DMODEL + h * DK;
    #pragma unroll
    for (int dt = 0; dt < 4; ++dt) {
      s16x4 ov;
      #pragma unroll
      for (int r = 0; r < 4; ++r) ov[r] = (short)bfc(oacc[hh][dt][r] * rn);
      *reinterpret_cast<s16x4*>(crow + dt * 16 + lg * 4) = ov;
    }
  }
}

// ---------------- output projection + bias + residual -> preLN (fp32) ------
__global__ __launch_bounds__(256) void out_gemm(
    const u16* __restrict__ ctx, const u16* __restrict__ Wob,
    const float* __restrict__ bo, const float* __restrict__ Qin,
    float* __restrict__ preLN)
{
  __shared__ u16 As[128 * 64], Bs[128 * 64];
  f32x4 acc[4][4] = {};
  gemm128_core(ctx, Wob, blockIdx.x, blockIdx.y, As, Bs, acc);

  const int lane = threadIdx.x & 63, wid = threadIdx.x >> 6;
  const int wr = wid >> 1, wc = wid & 1;
  #pragma unroll
  for (int j = 0; j < 4; ++j) {
    int n = blockIdx.y * 128 + wc * 64 + j * 16 + (lane & 15);
    float bv_ = bo[n];
    #pragma unroll
    for (int i = 0; i < 4; ++i) {
      int mbase = blockIdx.x * 128 + wr * 64 + i * 16 + (lane >> 4) * 4;
      #pragma unroll
      for (int r = 0; r < 4; ++r) {
        int m = mbase + r;
        preLN[(int64_t)m * DMODEL + n] = acc[i][j][r] + bv_ + Qin[(int64_t)m * DMODEL + n];
      }
    }
  }
}

// ---------------- LayerNorm: one wave per 512-elem row ----------------------
__global__ __launch_bounds__(256) void ln_kernel(
    const float* __restrict__ x, const float* __restrict__ gamma,
    const float* __restrict__ beta, float* __restrict__ out)
{
  const int row = blockIdx.x * 4 + (threadIdx.x >> 6);
  const int lane = threadIdx.x & 63;
  const float* xr = x + (int64_t)row * DMODEL;
  const int cbase = lane * 8;
  float4 a = *reinterpret_cast<const float4*>(xr + cbase);
  float4 c = *reinterpret_cast<const float4*>(xr + cbase + 4);
  float s = a.x + a.y + a.z + a.w + c.x + c.y + c.z + c.w;
  float s2 = a.x*a.x + a.y*a.y + a.z*a.z + a.w*a.w +
             c.x*c.x + c.y*c.y + c.z*c.z + c.w*c.w;
  #pragma unroll
  for (int m = 1; m < 64; m <<= 1) { s += __shfl_xor(s, m); s2 += __shfl_xor(s2, m); }
  float mu = s * (1.f / DMODEL);
  float var = s2 * (1.f / DMODEL) - mu * mu;
  float rstd = rsqrtf(var + 1e-5f);
  float4 g0 = *reinterpret_cast<const float4*>(gamma + cbase);
  float4 g1 = *reinterpret_cast<const float4*>(gamma + cbase + 4);
  float4 b0 = *reinterpret_cast<const float4*>(beta + cbase);
  float4 b1 = *reinterpret_cast<const float4*>(beta + cbase + 4);
  float4 o0, o1;
  o0.x = (a.x - mu) * rstd * g0.x + b0.x;
  o0.y = (a.y - mu) * rstd * g0.y + b0.y;
  o0.z = (a.z - mu) * rstd * g0.z + b0.z;
  o0.w = (a.w - mu) * rstd * g0.w + b0.w;
  o1.x = (c.x - mu) * rstd * g1.x + b1.x;
  o1.y = (c.y - mu) * rstd * g1.y + b1.y;
  o1.z = (c.z - mu) * rstd * g1.z + b1.z;
  o1.w = (c.w - mu) * rstd * g1.w + b1.w;
  float* orow = out + (int64_t)row * DMODEL;
  *reinterpret_cast<float4*>(orow + cbase) = o0;
  *reinterpret_cast<float4*>(orow + cbase + 4) = o1;
}

extern "C" void kernel_launch(void* const* d_in, const int* in_sizes, int n_in,
                              void* d_out, int out_size, void* d_ws, size_t ws_size,
                              hipStream_t stream) {
  (void)in_sizes; (void)n_in; (void)out_size; (void)ws_size;
  const float* Q     = (const float*)d_in[0];
  const float* K     = (const float*)d_in[1];
  const float* V     = (const float*)d_in[2];
  const float* Wq    = (const float*)d_in[3];
  const float* bq    = (const float*)d_in[4];
  const float* Wk    = (const float*)d_in[5];
  const float* bk    = (const float*)d_in[6];
  const float* Wv    = (const float*)d_in[7];
  const float* bv    = (const float*)d_in[8];
  const float* Wo    = (const float*)d_in[9];
  const float* bo    = (const float*)d_in[10];
  const float* gamma = (const float*)d_in[11];
  const float* beta  = (const float*)d_in[12];
  float* out = (float*)d_out;

  const int NBIG = MTOT * DMODEL;   // 4194304 elems
  const int NW = DMODEL * DMODEL;   // 262144 elems
  u16* wsp = (u16*)d_ws;
  u16* Qb  = wsp;
  u16* Kb  = Qb + NBIG;
  u16* Vb  = Kb + NBIG;
  u16* Wqb = Vb + NBIG;
  u16* Wkb = Wqb + NW;
  u16* Wvb = Wkb + NW;
  u16* Wob = Wvb + NW;
  u16* qh  = Wob + NW;
  u16* kh  = qh + NBIG;
  u16* vh  = kh + NBIG;
  u16* ctx = vh + NBIG;
  float* preLN = (float*)Qb;  // aliases Qb+Kb (16MB) — dead by out_gemm time

  convert_kernel<<<dim3(2048), 256, 0, stream>>>(Q, K, V, Wq, Wk, Wv, Wo,
                                                 Qb, Kb, Vb, Wqb, Wkb, Wvb, Wob);
  qkv_gemm<<<dim3(64, 4, 3), 256, 0, stream>>>(Qb, Kb, Vb, Wqb, Wkb, Wvb,
                                               bq, bk, bv, qh, kh, vh);
  attn_kernel<<<dim3(16, 32), 256, 0, stream>>>(qh, kh, vh, ctx);
  out_gemm<<<dim3(64, 4), 256, 0, stream>>>(ctx, Wob, bo, Q, preLN);
  ln_kernel<<<dim3(2048), 256, 0, stream>>>(preLN, gamma, beta, out);
}

// Round 7
// 131.720 us; speedup vs baseline: 1.0151x; 1.0151x over previous
//
#include <hip/hip_runtime.h>
#include <cstdint>

#define DMODEL 512
#define NH 8
#define DK 64
#define SS 2048
#define MTOT 8192

typedef unsigned short u16;
typedef __bf16 bf16_t;
typedef bf16_t bf16x8 __attribute__((ext_vector_type(8)));
typedef short s16x4 __attribute__((ext_vector_type(4)));
typedef float f32x4 __attribute__((ext_vector_type(4)));

// hardware exp2 (v_exp_f32)
__device__ __forceinline__ float exp2_hw(float x) {
  return __builtin_amdgcn_exp2f(x);
}

// hardware RNE f32->bf16
__device__ __forceinline__ u16 bfc(float f) {
  __bf16 h = (__bf16)f;
  return __builtin_bit_cast(u16, h);
}

__device__ __forceinline__ void gload_lds16(const void* g, void* l) {
  __builtin_amdgcn_global_load_lds(
      (const __attribute__((address_space(1))) unsigned int*)g,
      (__attribute__((address_space(3))) unsigned int*)l, 16, 0, 0);
}

// ---------------- fp32 -> bf16 conversion (inputs + weights) ----------------
__global__ __launch_bounds__(256) void convert_kernel(
    const float* __restrict__ Q, const float* __restrict__ K, const float* __restrict__ V,
    const float* __restrict__ Wq, const float* __restrict__ Wk,
    const float* __restrict__ Wv, const float* __restrict__ Wo,
    u16* __restrict__ Qb, u16* __restrict__ Kb, u16* __restrict__ Vb,
    u16* __restrict__ Wqb, u16* __restrict__ Wkb, u16* __restrict__ Wvb,
    u16* __restrict__ Wob)
{
  const int NBIG = MTOT * DMODEL;      // 4194304
  const int NW = DMODEL * DMODEL;      // 262144
  const int TOT4 = (3 * NBIG + 4 * NW) / 4;
  for (int i = blockIdx.x * blockDim.x + threadIdx.x; i < TOT4;
       i += gridDim.x * blockDim.x) {
    int e = i * 4;
    const float* src; u16* dst; int off;
    if (e < 3 * NBIG) {
      int w = e / NBIG; off = e - w * NBIG;
      src = (w == 0) ? Q : (w == 1) ? K : V;
      dst = (w == 0) ? Qb : (w == 1) ? Kb : Vb;
    } else {
      int e2 = e - 3 * NBIG; int w = e2 / NW; off = e2 - w * NW;
      src = (w == 0) ? Wq : (w == 1) ? Wk : (w == 2) ? Wv : Wo;
      dst = (w == 0) ? Wqb : (w == 1) ? Wkb : (w == 2) ? Wvb : Wob;
    }
    float4 v = *reinterpret_cast<const float4*>(src + off);
    uint64_t p = (uint64_t)bfc(v.x) | ((uint64_t)bfc(v.y) << 16) |
                 ((uint64_t)bfc(v.z) << 32) | ((uint64_t)bfc(v.w) << 48);
    *reinterpret_cast<uint64_t*>(dst + off) = p;
  }
}

// ---------------- 128x128 GEMM core: C = X @ W^T (both K-contiguous) --------
// 256 threads = 4 waves (2x2), each wave 64x64 (4x4 frags of 16x16x32 bf16)
// LDS tiles XOR-swizzled: 16B slot s of row r holds global slot s^(r&7).
__device__ __forceinline__ void gemm128_core(
    const u16* __restrict__ X, const u16* __restrict__ W,
    int bm, int bn, u16* As, u16* Bs, f32x4 (&acc)[4][4])
{
  const int tid = threadIdx.x;
  const int wid = tid >> 6, lane = tid & 63;
  const int wr = wid >> 1, wc = wid & 1;
  const int lrow = lane >> 3;
  const int lcolS = (((lane & 7) ^ lrow) * 8);   // pre-swizzled source column
  const int l15 = lane & 15, lg = lane >> 4;
  const u16* Ab = X + (int64_t)bm * 128 * DMODEL;
  const u16* Bb = W + (int64_t)bn * 128 * DMODEL;
  for (int k0 = 0; k0 < DMODEL; k0 += 64) {
    __syncthreads();
    #pragma unroll
    for (int j = 0; j < 4; ++j) {
      int c = wid * 4 + j;                    // chunk: rows c*8..c*8+7
      gload_lds16(Ab + (int64_t)(c * 8 + lrow) * DMODEL + k0 + lcolS, As + c * 512);
      gload_lds16(Bb + (int64_t)(c * 8 + lrow) * DMODEL + k0 + lcolS, Bs + c * 512);
    }
    asm volatile("s_waitcnt vmcnt(0)" ::: "memory");
    __syncthreads();
    #pragma unroll
    for (int kk = 0; kk < 2; ++kk) {
      bf16x8 af[4], bfr[4];
      #pragma unroll
      for (int i = 0; i < 4; ++i) {
        int rowA = wr * 64 + i * 16 + l15;
        int rowB = wc * 64 + i * 16 + l15;
        int slot = ((kk * 4 + lg) ^ (l15 & 7)) * 8;
        af[i]  = *reinterpret_cast<const bf16x8*>(As + rowA * 64 + slot);
        bfr[i] = *reinterpret_cast<const bf16x8*>(Bs + rowB * 64 + slot);
      }
      #pragma unroll
      for (int i = 0; i < 4; ++i)
        #pragma unroll
        for (int j = 0; j < 4; ++j)
          acc[i][j] = __builtin_amdgcn_mfma_f32_16x16x32_bf16(af[i], bfr[j], acc[i][j], 0, 0, 0);
    }
  }
}

// ---------------- QKV projection: out scattered to per-head layout ----------
// q,k: [B][H][S][DK] bf16 ; v: [B][H][DK][S] bf16 (pre-transposed for attn)
// K rows pre-scaled by (1/sqrt(dk))*log2(e) so attn exp2 needs no multiply.
#define C_QK 0.18033688011112043f   // (1/8) * log2(e)
__global__ __launch_bounds__(256) void qkv_gemm(
    const u16* __restrict__ Qb, const u16* __restrict__ Kb, const u16* __restrict__ Vb,
    const u16* __restrict__ Wqb, const u16* __restrict__ Wkb, const u16* __restrict__ Wvb,
    const float* __restrict__ bq, const float* __restrict__ bk, const float* __restrict__ bv,
    u16* __restrict__ qh, u16* __restrict__ kh, u16* __restrict__ vh)
{
  __shared__ u16 As[128 * 64], Bs[128 * 64];
  const int z = blockIdx.z;
  const u16* X = (z == 0) ? Qb : (z == 1) ? Kb : Vb;
  const u16* W = (z == 0) ? Wqb : (z == 1) ? Wkb : Wvb;
  const float* bias = (z == 0) ? bq : (z == 1) ? bk : bv;
  u16* out = (z == 0) ? qh : (z == 1) ? kh : vh;
  const float scale = (z == 1) ? C_QK : 1.0f;

  f32x4 acc[4][4] = {};
  gemm128_core(X, W, blockIdx.x, blockIdx.y, As, Bs, acc);

  const int lane = threadIdx.x & 63, wid = threadIdx.x >> 6;
  const int wr = wid >> 1, wc = wid & 1;
  #pragma unroll
  for (int j = 0; j < 4; ++j) {
    int n = blockIdx.y * 128 + wc * 64 + j * 16 + (lane & 15);
    float bv_ = bias[n];
    int h = n >> 6, d = n & 63;
    #pragma unroll
    for (int i = 0; i < 4; ++i) {
      int mbase = blockIdx.x * 128 + wr * 64 + i * 16 + (lane >> 4) * 4;
      #pragma unroll
      for (int r = 0; r < 4; ++r) {
        int m = mbase + r;
        int b = m >> 11, s = m & 2047;
        u16 val = bfc((acc[i][j][r] + bv_) * scale);
        if (z == 2)
          out[((int64_t)(b * NH + h) * DK + d) * SS + s] = val;
        else
          out[((int64_t)((b * NH + h) * SS + s) << 6) | d] = val;
      }
    }
  }
}

// ---------------- flash attention: 64 q-rows/block, KV tiles of 64 ----------
// XCD-swizzled grid: each XCD owns 4 heads -> K/V stays in its private L2.
// Counted-vmcnt double-buffer: issue next tile's global_load_lds, then
// vmcnt(4) waits only the PREVIOUS tile's 4 loads (a full iteration in
// flight). Swapped QK^T -> P^T in regs; packed P staged via per-wave LDS
// (b64 writes, b128 reads, XOR-swizzled); PV = K=32 mfma, conflict-free.
__global__ __launch_bounds__(256) void attn_kernel(
    const u16* __restrict__ qh, const u16* __restrict__ kh, const u16* __restrict__ vh,
    u16* __restrict__ ctx)
{
  __shared__ u16 Ks[2][64 * 64];
  __shared__ u16 Vts[2][64 * 64];   // [d][k] (source pre-transposed in global)
  __shared__ u16 Ps[4][16 * 64];    // per-wave packed P tile [q][key]

  // XCD-aware decode: wg&7 ~ XCD id (round-robin dispatch heuristic).
  // Each XCD gets heads {x, x+8, x+16, x+24} -> 2MB K/V resident in its L2.
  const int wg = blockIdx.x;            // 0..1023
  const int xcd = wg & 7;
  const int i = wg >> 3;                // 0..127
  const int bh = xcd + 8 * (i & 3);     // 0..31
  const int qt = i >> 2;                // 0..31
  const int b = bh >> 3, h = bh & 7;
  const u16* Qp = qh + (int64_t)bh * SS * DK;
  const u16* Kp = kh + (int64_t)bh * SS * DK;
  const u16* Vp = vh + (int64_t)bh * SS * DK;  // [DK][SS] per head

  const int tid = threadIdx.x;
  const int wid = tid >> 6, lane = tid & 63;
  const int l15 = lane & 15, lg = lane >> 4;
  const int m7 = l15 & 7;
  const int lrow = lane >> 3;
  const int lcolS = (((lane & 7) ^ lrow) * 8);  // pre-swizzled source column

  bf16x8 qf[2];
  {
    const u16* qrow = Qp + (int64_t)(qt * 64 + wid * 16 + l15) * DK + lg * 8;
    qf[0] = *reinterpret_cast<const bf16x8*>(qrow);
    qf[1] = *reinterpret_cast<const bf16x8*>(qrow + 32);
  }

  f32x4 oacc[4] = {};
  f32x4 lsumv = {};
  u16* Pw = &Ps[wid][0];

  // prologue: stage tile 0 into buffer 0 (4 loads/wave)
  #pragma unroll
  for (int j = 0; j < 2; ++j) {
    int c = wid * 2 + j;
    gload_lds16(Kp + (int64_t)(c * 8 + lrow) * DK + lcolS, Ks[0] + c * 512);
    gload_lds16(Vp + (int64_t)(c * 8 + lrow) * SS + lcolS, Vts[0] + c * 512);
  }

  const int NT = SS / 64;
  for (int kt = 0; kt < NT; ++kt) {
    const int cur = kt & 1;
    if (kt + 1 < NT) {
      // issue next tile's 4 loads into the other buffer, then wait only for
      // the previous 4 (this tile's) -> next tile has a full iter to land
      #pragma unroll
      for (int j = 0; j < 2; ++j) {
        int c = wid * 2 + j;
        gload_lds16(Kp + (int64_t)((kt + 1) * 64 + c * 8 + lrow) * DK + lcolS,
                    Ks[cur ^ 1] + c * 512);
        gload_lds16(Vp + (int64_t)(c * 8 + lrow) * SS + (kt + 1) * 64 + lcolS,
                    Vts[cur ^ 1] + c * 512);
      }
      asm volatile("s_waitcnt vmcnt(4)" ::: "memory");
    } else {
      asm volatile("s_waitcnt vmcnt(0)" ::: "memory");
    }
    __syncthreads();   // tile kt staged by ALL waves

    // swapped QK^T: sacc[nt][r] = S[q=l15][key=nt*16+lg*4+r]
    f32x4 sacc[4] = {};
    #pragma unroll
    for (int ks = 0; ks < 2; ++ks) {
      #pragma unroll
      for (int nt = 0; nt < 4; ++nt) {
        int slot = ((ks * 4 + lg) ^ m7) * 8;
        bf16x8 kf = *reinterpret_cast<const bf16x8*>(
            Ks[cur] + (nt * 16 + l15) * 64 + slot);
        sacc[nt] = __builtin_amdgcn_mfma_f32_16x16x32_bf16(kf, qf[ks], sacc[nt], 0, 0, 0);
      }
    }

    // fixed-max softmax: P = 2^s (K pre-scaled); pack pairs, 8B writes to Ps
    #pragma unroll
    for (int nt = 0; nt < 4; ++nt) {
      f32x4 p;
      #pragma unroll
      for (int r = 0; r < 4; ++r) p[r] = exp2_hw(sacc[nt][r]);
      lsumv += p;
      uint32_t lo = (uint32_t)bfc(p[0]) | ((uint32_t)bfc(p[1]) << 16);
      uint32_t hi = (uint32_t)bfc(p[2]) | ((uint32_t)bfc(p[3]) << 16);
      uint64_t pk2 = ((uint64_t)hi << 32) | lo;
      // row l15, keys nt*16+lg*4..+3 -> slot (2nt+(lg>>1))^m7, half lg&1
      *reinterpret_cast<uint64_t*>(
          Pw + l15 * 64 + (((2 * nt + (lg >> 1)) ^ m7) * 8) + (lg & 1) * 4) = pk2;
    }

    // PV: O^T[d][q] += V^T[d][k] @ P^T[k][q], K=32 mfma, full-slot b128 reads
    #pragma unroll
    for (int kg = 0; kg < 2; ++kg) {
      int slot = ((kg * 4 + lg) ^ m7) * 8;
      bf16x8 pb = *reinterpret_cast<const bf16x8*>(Pw + l15 * 64 + slot);
      #pragma unroll
      for (int dt = 0; dt < 4; ++dt) {
        bf16x8 vt = *reinterpret_cast<const bf16x8*>(
            Vts[cur] + (dt * 16 + l15) * 64 + slot);
        oacc[dt] = __builtin_amdgcn_mfma_f32_16x16x32_bf16(vt, pb, oacc[dt], 0, 0, 0);
      }
    }

    __syncthreads();   // all waves done reading buf[cur] (overwritten next iter)
  }

  // row-sum: lane partial covers keys {lg*4+r}; combine across 4 lane-groups
  float lsum = lsumv[0] + lsumv[1] + lsumv[2] + lsumv[3];
  lsum += __shfl_xor(lsum, 16);
  lsum += __shfl_xor(lsum, 32);
  float rn = 1.f / lsum;

  const int q = qt * 64 + wid * 16 + l15;
  u16* crow = ctx + (int64_t)(b * SS + q) * DMODEL + h * DK;
  #pragma unroll
  for (int dt = 0; dt < 4; ++dt) {
    s16x4 ov;
    #pragma unroll
    for (int r = 0; r < 4; ++r) ov[r] = (short)bfc(oacc[dt][r] * rn);
    *reinterpret_cast<s16x4*>(crow + dt * 16 + lg * 4) = ov;
  }
}

// ---------------- output projection + bias + residual -> preLN (fp32) ------
__global__ __launch_bounds__(256) void out_gemm(
    const u16* __restrict__ ctx, const u16* __restrict__ Wob,
    const float* __restrict__ bo, const float* __restrict__ Qin,
    float* __restrict__ preLN)
{
  __shared__ u16 As[128 * 64], Bs[128 * 64];
  f32x4 acc[4][4] = {};
  gemm128_core(ctx, Wob, blockIdx.x, blockIdx.y, As, Bs, acc);

  const int lane = threadIdx.x & 63, wid = threadIdx.x >> 6;
  const int wr = wid >> 1, wc = wid & 1;
  #pragma unroll
  for (int j = 0; j < 4; ++j) {
    int n = blockIdx.y * 128 + wc * 64 + j * 16 + (lane & 15);
    float bv_ = bo[n];
    #pragma unroll
    for (int i = 0; i < 4; ++i) {
      int mbase = blockIdx.x * 128 + wr * 64 + i * 16 + (lane >> 4) * 4;
      #pragma unroll
      for (int r = 0; r < 4; ++r) {
        int m = mbase + r;
        preLN[(int64_t)m * DMODEL + n] = acc[i][j][r] + bv_ + Qin[(int64_t)m * DMODEL + n];
      }
    }
  }
}

// ---------------- LayerNorm: one wave per 512-elem row ----------------------
__global__ __launch_bounds__(256) void ln_kernel(
    const float* __restrict__ x, const float* __restrict__ gamma,
    const float* __restrict__ beta, float* __restrict__ out)
{
  const int row = blockIdx.x * 4 + (threadIdx.x >> 6);
  const int lane = threadIdx.x & 63;
  const float* xr = x + (int64_t)row * DMODEL;
  const int cbase = lane * 8;
  float4 a = *reinterpret_cast<const float4*>(xr + cbase);
  float4 c = *reinterpret_cast<const float4*>(xr + cbase + 4);
  float s = a.x + a.y + a.z + a.w + c.x + c.y + c.z + c.w;
  float s2 = a.x*a.x + a.y*a.y + a.z*a.z + a.w*a.w +
             c.x*c.x + c.y*c.y + c.z*c.z + c.w*c.w;
  #pragma unroll
  for (int m = 1; m < 64; m <<= 1) { s += __shfl_xor(s, m); s2 += __shfl_xor(s2, m); }
  float mu = s * (1.f / DMODEL);
  float var = s2 * (1.f / DMODEL) - mu * mu;
  float rstd = rsqrtf(var + 1e-5f);
  float4 g0 = *reinterpret_cast<const float4*>(gamma + cbase);
  float4 g1 = *reinterpret_cast<const float4*>(gamma + cbase + 4);
  float4 b0 = *reinterpret_cast<const float4*>(beta + cbase);
  float4 b1 = *reinterpret_cast<const float4*>(beta + cbase + 4);
  float4 o0, o1;
  o0.x = (a.x - mu) * rstd * g0.x + b0.x;
  o0.y = (a.y - mu) * rstd * g0.y + b0.y;
  o0.z = (a.z - mu) * rstd * g0.z + b0.z;
  o0.w = (a.w - mu) * rstd * g0.w + b0.w;
  o1.x = (c.x - mu) * rstd * g1.x + b1.x;
  o1.y = (c.y - mu) * rstd * g1.y + b1.y;
  o1.z = (c.z - mu) * rstd * g1.z + b1.z;
  o1.w = (c.w - mu) * rstd * g1.w + b1.w;
  float* orow = out + (int64_t)row * DMODEL;
  *reinterpret_cast<float4*>(orow + cbase) = o0;
  *reinterpret_cast<float4*>(orow + cbase + 4) = o1;
}

extern "C" void kernel_launch(void* const* d_in, const int* in_sizes, int n_in,
                              void* d_out, int out_size, void* d_ws, size_t ws_size,
                              hipStream_t stream) {
  (void)in_sizes; (void)n_in; (void)out_size; (void)ws_size;
  const float* Q     = (const float*)d_in[0];
  const float* K     = (const float*)d_in[1];
  const float* V     = (const float*)d_in[2];
  const float* Wq    = (const float*)d_in[3];
  const float* bq    = (const float*)d_in[4];
  const float* Wk    = (const float*)d_in[5];
  const float* bk    = (const float*)d_in[6];
  const float* Wv    = (const float*)d_in[7];
  const float* bv    = (const float*)d_in[8];
  const float* Wo    = (const float*)d_in[9];
  const float* bo    = (const float*)d_in[10];
  const float* gamma = (const float*)d_in[11];
  const float* beta  = (const float*)d_in[12];
  float* out = (float*)d_out;

  const int NBIG = MTOT * DMODEL;   // 4194304 elems
  const int NW = DMODEL * DMODEL;   // 262144 elems
  u16* wsp = (u16*)d_ws;
  u16* Qb  = wsp;
  u16* Kb  = Qb + NBIG;
  u16* Vb  = Kb + NBIG;
  u16* Wqb = Vb + NBIG;
  u16* Wkb = Wqb + NW;
  u16* Wvb = Wkb + NW;
  u16* Wob = Wvb + NW;
  u16* qh  = Wob + NW;
  u16* kh  = qh + NBIG;
  u16* vh  = kh + NBIG;
  u16* ctx = vh + NBIG;
  float* preLN = (float*)Qb;  // aliases Qb+Kb (16MB) — dead by out_gemm time

  convert_kernel<<<dim3(2048), 256, 0, stream>>>(Q, K, V, Wq, Wk, Wv, Wo,
                                                 Qb, Kb, Vb, Wqb, Wkb, Wvb, Wob);
  qkv_gemm<<<dim3(64, 4, 3), 256, 0, stream>>>(Qb, Kb, Vb, Wqb, Wkb, Wvb,
                                               bq, bk, bv, qh, kh, vh);
  attn_kernel<<<dim3(1024), 256, 0, stream>>>(qh, kh, vh, ctx);
  out_gemm<<<dim3(64, 4), 256, 0, stream>>>(ctx, Wob, bo, Q, preLN);
  ln_kernel<<<dim3(2048), 256, 0, stream>>>(preLN, gamma, beta, out);
}

// Round 8
// 121.221 us; speedup vs baseline: 1.1030x; 1.0866x over previous
//
#include <hip/hip_runtime.h>
#include <cstdint>

#define DMODEL 512
#define NH 8
#define DK 64
#define SS 2048
#define MTOT 8192

typedef unsigned short u16;
typedef __bf16 bf16_t;
typedef bf16_t bf16x8 __attribute__((ext_vector_type(8)));
typedef short s16x4 __attribute__((ext_vector_type(4)));
typedef float f32x4 __attribute__((ext_vector_type(4)));

// hardware exp2 (v_exp_f32)
__device__ __forceinline__ float exp2_hw(float x) {
  return __builtin_amdgcn_exp2f(x);
}

// hardware RNE f32->bf16
__device__ __forceinline__ u16 bfc(float f) {
  __bf16 h = (__bf16)f;
  return __builtin_bit_cast(u16, h);
}

__device__ __forceinline__ void gload_lds16(const void* g, void* l) {
  __builtin_amdgcn_global_load_lds(
      (const __attribute__((address_space(1))) unsigned int*)g,
      (__attribute__((address_space(3))) unsigned int*)l, 16, 0, 0);
}

// ---------------- fp32 -> bf16 conversion (inputs + weights) ----------------
__global__ __launch_bounds__(256) void convert_kernel(
    const float* __restrict__ Q, const float* __restrict__ K, const float* __restrict__ V,
    const float* __restrict__ Wq, const float* __restrict__ Wk,
    const float* __restrict__ Wv, const float* __restrict__ Wo,
    u16* __restrict__ Qb, u16* __restrict__ Kb, u16* __restrict__ Vb,
    u16* __restrict__ Wqb, u16* __restrict__ Wkb, u16* __restrict__ Wvb,
    u16* __restrict__ Wob)
{
  const int NBIG = MTOT * DMODEL;      // 4194304
  const int NW = DMODEL * DMODEL;      // 262144
  const int TOT4 = (3 * NBIG + 4 * NW) / 4;
  for (int i = blockIdx.x * blockDim.x + threadIdx.x; i < TOT4;
       i += gridDim.x * blockDim.x) {
    int e = i * 4;
    const float* src; u16* dst; int off;
    if (e < 3 * NBIG) {
      int w = e / NBIG; off = e - w * NBIG;
      src = (w == 0) ? Q : (w == 1) ? K : V;
      dst = (w == 0) ? Qb : (w == 1) ? Kb : Vb;
    } else {
      int e2 = e - 3 * NBIG; int w = e2 / NW; off = e2 - w * NW;
      src = (w == 0) ? Wq : (w == 1) ? Wk : (w == 2) ? Wv : Wo;
      dst = (w == 0) ? Wqb : (w == 1) ? Wkb : (w == 2) ? Wvb : Wob;
    }
    float4 v = *reinterpret_cast<const float4*>(src + off);
    uint64_t p = (uint64_t)bfc(v.x) | ((uint64_t)bfc(v.y) << 16) |
                 ((uint64_t)bfc(v.z) << 32) | ((uint64_t)bfc(v.w) << 48);
    *reinterpret_cast<uint64_t*>(dst + off) = p;
  }
}

// ---------------- 128x128 GEMM core: C = X @ W^T (both K-contiguous) --------
__device__ __forceinline__ void gemm128_core(
    const u16* __restrict__ X, const u16* __restrict__ W,
    int bm, int bn, u16* As, u16* Bs, f32x4 (&acc)[4][4])
{
  const int tid = threadIdx.x;
  const int wid = tid >> 6, lane = tid & 63;
  const int wr = wid >> 1, wc = wid & 1;
  const int lrow = lane >> 3;
  const int lcolS = (((lane & 7) ^ lrow) * 8);   // pre-swizzled source column
  const int l15 = lane & 15, lg = lane >> 4;
  const u16* Ab = X + (int64_t)bm * 128 * DMODEL;
  const u16* Bb = W + (int64_t)bn * 128 * DMODEL;
  for (int k0 = 0; k0 < DMODEL; k0 += 64) {
    __syncthreads();
    #pragma unroll
    for (int j = 0; j < 4; ++j) {
      int c = wid * 4 + j;                    // chunk: rows c*8..c*8+7
      gload_lds16(Ab + (int64_t)(c * 8 + lrow) * DMODEL + k0 + lcolS, As + c * 512);
      gload_lds16(Bb + (int64_t)(c * 8 + lrow) * DMODEL + k0 + lcolS, Bs + c * 512);
    }
    asm volatile("s_waitcnt vmcnt(0)" ::: "memory");
    __syncthreads();
    #pragma unroll
    for (int kk = 0; kk < 2; ++kk) {
      bf16x8 af[4], bfr[4];
      #pragma unroll
      for (int i = 0; i < 4; ++i) {
        int rowA = wr * 64 + i * 16 + l15;
        int rowB = wc * 64 + i * 16 + l15;
        int slot = ((kk * 4 + lg) ^ (l15 & 7)) * 8;
        af[i]  = *reinterpret_cast<const bf16x8*>(As + rowA * 64 + slot);
        bfr[i] = *reinterpret_cast<const bf16x8*>(Bs + rowB * 64 + slot);
      }
      #pragma unroll
      for (int i = 0; i < 4; ++i)
        #pragma unroll
        for (int j = 0; j < 4; ++j)
          acc[i][j] = __builtin_amdgcn_mfma_f32_16x16x32_bf16(af[i], bfr[j], acc[i][j], 0, 0, 0);
    }
  }
}

// ---------------- QKV projection: out scattered to per-head layout ----------
// q,k: [B][H][S][DK] bf16 ; v: [B][H][DK][S] bf16 (pre-transposed for attn)
// K rows pre-scaled by (1/sqrt(dk))*log2(e) so attn exp2 needs no multiply.
#define C_QK 0.18033688011112043f   // (1/8) * log2(e)
__global__ __launch_bounds__(256) void qkv_gemm(
    const u16* __restrict__ Qb, const u16* __restrict__ Kb, const u16* __restrict__ Vb,
    const u16* __restrict__ Wqb, const u16* __restrict__ Wkb, const u16* __restrict__ Wvb,
    const float* __restrict__ bq, const float* __restrict__ bk, const float* __restrict__ bv,
    u16* __restrict__ qh, u16* __restrict__ kh, u16* __restrict__ vh)
{
  __shared__ u16 As[128 * 64], Bs[128 * 64];
  const int z = blockIdx.z;
  const u16* X = (z == 0) ? Qb : (z == 1) ? Kb : Vb;
  const u16* W = (z == 0) ? Wqb : (z == 1) ? Wkb : Wvb;
  const float* bias = (z == 0) ? bq : (z == 1) ? bk : bv;
  u16* out = (z == 0) ? qh : (z == 1) ? kh : vh;
  const float scale = (z == 1) ? C_QK : 1.0f;

  f32x4 acc[4][4] = {};
  gemm128_core(X, W, blockIdx.x, blockIdx.y, As, Bs, acc);

  const int lane = threadIdx.x & 63, wid = threadIdx.x >> 6;
  const int wr = wid >> 1, wc = wid & 1;
  #pragma unroll
  for (int j = 0; j < 4; ++j) {
    int n = blockIdx.y * 128 + wc * 64 + j * 16 + (lane & 15);
    float bv_ = bias[n];
    int h = n >> 6, d = n & 63;
    #pragma unroll
    for (int i = 0; i < 4; ++i) {
      int mbase = blockIdx.x * 128 + wr * 64 + i * 16 + (lane >> 4) * 4;
      #pragma unroll
      for (int r = 0; r < 4; ++r) {
        int m = mbase + r;
        int b = m >> 11, s = m & 2047;
        u16 val = bfc((acc[i][j][r] + bv_) * scale);
        if (z == 2)
          out[((int64_t)(b * NH + h) * DK + d) * SS + s] = val;
        else
          out[((int64_t)((b * NH + h) * SS + s) << 6) | d] = val;
      }
    }
  }
}

// ---------------- flash attention: 128 q-rows/block, KV tiles of 64 ---------
// 32 q-rows/wave (2 halves): every K/V LDS fragment read feeds 2x MFMA.
// All LDS addresses hoisted to loop-invariant pointers (buffer parity via
// macro literal). Row-sum via ones-MFMA. XCD-swizzled grid; counted vmcnt.
__global__ __launch_bounds__(256) void attn_kernel(
    const u16* __restrict__ qh, const u16* __restrict__ kh, const u16* __restrict__ vh,
    u16* __restrict__ ctx)
{
  __shared__ u16 Ks[2][64 * 64];
  __shared__ u16 Vts[2][64 * 64];   // [d][k] (source pre-transposed in global)
  __shared__ u16 Ps[4][2][16 * 64]; // per-wave, per-half packed P^T tile

  // XCD-aware decode: each XCD owns 4 heads -> K/V resident in its 4MB L2.
  const int wg = blockIdx.x;            // 0..511
  const int xcd = wg & 7;
  const int i = wg >> 3;                // 0..63
  const int bh = xcd + 8 * (i & 3);     // 0..31
  const int qt = i >> 2;                // 0..15, 128 q-rows per block
  const int b = bh >> 3, h = bh & 7;
  const u16* Qp = qh + (int64_t)bh * SS * DK;
  const u16* Kp = kh + (int64_t)bh * SS * DK;
  const u16* Vp = vh + (int64_t)bh * SS * DK;  // [DK][SS] per head

  const int tid = threadIdx.x;
  const int wid = tid >> 6, lane = tid & 63;
  const int l15 = lane & 15, lg = lane >> 4;
  const int m7 = l15 & 7;
  const int lrow = lane >> 3;
  const int lcolS = (((lane & 7) ^ lrow) * 8);  // pre-swizzled source column

  // Q fragments, two 16-row halves
  bf16x8 qf0[2], qf1[2];
  {
    const u16* q0 = Qp + (int64_t)(qt * 128 + wid * 32 + l15) * DK + lg * 8;
    qf0[0] = *reinterpret_cast<const bf16x8*>(q0);
    qf0[1] = *reinterpret_cast<const bf16x8*>(q0 + 32);
    const u16* q1 = q0 + 16 * DK;
    qf1[0] = *reinterpret_cast<const bf16x8*>(q1);
    qf1[1] = *reinterpret_cast<const bf16x8*>(q1 + 32);
  }

  bf16x8 ones;
  #pragma unroll
  for (int e = 0; e < 8; ++e) ones[e] = (__bf16)1.0f;

  f32x4 o0[4] = {}, o1[4] = {};
  f32x4 la0 = {}, la1 = {};

  // ---- hoisted loop-invariant LDS addresses (u16 units) ----
  const int rowB = l15 * 64;
  const int sl0 = (lg ^ m7) * 8;         // ks/kg = 0
  const int sl1 = ((4 + lg) ^ m7) * 8;   // ks/kg = 1
  const u16* kf0_0 = &Ks[0][0] + rowB + sl0;
  const u16* kf0_1 = &Ks[0][0] + rowB + sl1;
  const u16* kf1_0 = &Ks[1][0] + rowB + sl0;
  const u16* kf1_1 = &Ks[1][0] + rowB + sl1;
  const u16* vt0_0 = &Vts[0][0] + rowB + sl0;
  const u16* vt0_1 = &Vts[0][0] + rowB + sl1;
  const u16* vt1_0 = &Vts[1][0] + rowB + sl0;
  const u16* vt1_1 = &Vts[1][0] + rowB + sl1;
  u16* Pw = &Ps[wid][0][0];
  u16* pwA[4];
  #pragma unroll
  for (int nt = 0; nt < 4; ++nt)
    pwA[nt] = Pw + rowB + (((2 * nt + (lg >> 1)) ^ m7) * 8) + (lg & 1) * 4;
  const u16* pr0 = Pw + rowB + sl0;
  const u16* pr1 = Pw + rowB + sl1;

  // ---- staging (per wave: rows c0*8.. and c1*8.. of the 64-row tile) ----
  const int c0 = wid * 2, c1 = c0 + 1;
  const u16* srcK = Kp + (c0 * 8 + lrow) * DK + lcolS;      // +512 for c1
  const u16* srcV = Vp + (int64_t)(c0 * 8 + lrow) * SS + lcolS;  // +8*SS for c1
  u16* dK0_0 = &Ks[0][0] + c0 * 512; u16* dK0_1 = &Ks[0][0] + c1 * 512;
  u16* dK1_0 = &Ks[1][0] + c0 * 512; u16* dK1_1 = &Ks[1][0] + c1 * 512;
  u16* dV0_0 = &Vts[0][0] + c0 * 512; u16* dV0_1 = &Vts[0][0] + c1 * 512;
  u16* dV1_0 = &Vts[1][0] + c0 * 512; u16* dV1_1 = &Vts[1][0] + c1 * 512;

  // prologue: tile 0 -> buffer 0
  gload_lds16(srcK, dK0_0);
  gload_lds16(srcK + 512, dK0_1);
  gload_lds16(srcV, dV0_0);
  gload_lds16(srcV + 8 * SS, dV0_1);

  const int NT = SS / 64;

#define ATTN_TILE(kt, R, W)                                                    \
  {                                                                            \
    if ((kt) + 1 < NT) {                                                       \
      const int64_t a1 = (int64_t)((kt) + 1);                                  \
      gload_lds16(srcK + a1 * (64 * DK), dK##W##_0);                           \
      gload_lds16(srcK + a1 * (64 * DK) + 512, dK##W##_1);                     \
      gload_lds16(srcV + a1 * 64, dV##W##_0);                                  \
      gload_lds16(srcV + a1 * 64 + 8 * SS, dV##W##_1);                         \
      asm volatile("s_waitcnt vmcnt(4)" ::: "memory");                         \
    } else {                                                                   \
      asm volatile("s_waitcnt vmcnt(0)" ::: "memory");                         \
    }                                                                          \
    __syncthreads();                                                           \
    f32x4 s0[4] = {}, s1[4] = {};                                              \
    _Pragma("unroll") for (int nt = 0; nt < 4; ++nt) {                         \
      bf16x8 kfa = *reinterpret_cast<const bf16x8*>(kf##R##_0 + nt * 1024);    \
      bf16x8 kfb = *reinterpret_cast<const bf16x8*>(kf##R##_1 + nt * 1024);    \
      s0[nt] = __builtin_amdgcn_mfma_f32_16x16x32_bf16(kfa, qf0[0], s0[nt], 0, 0, 0); \
      s1[nt] = __builtin_amdgcn_mfma_f32_16x16x32_bf16(kfa, qf1[0], s1[nt], 0, 0, 0); \
      s0[nt] = __builtin_amdgcn_mfma_f32_16x16x32_bf16(kfb, qf0[1], s0[nt], 0, 0, 0); \
      s1[nt] = __builtin_amdgcn_mfma_f32_16x16x32_bf16(kfb, qf1[1], s1[nt], 0, 0, 0); \
    }                                                                          \
    _Pragma("unroll") for (int nt = 0; nt < 4; ++nt) {                         \
      uint32_t w0 = (uint32_t)bfc(exp2_hw(s0[nt][0])) |                        \
                    ((uint32_t)bfc(exp2_hw(s0[nt][1])) << 16);                 \
      uint32_t w1 = (uint32_t)bfc(exp2_hw(s0[nt][2])) |                        \
                    ((uint32_t)bfc(exp2_hw(s0[nt][3])) << 16);                 \
      *reinterpret_cast<uint64_t*>(pwA[nt]) =                                  \
          (uint64_t)w0 | ((uint64_t)w1 << 32);                                 \
      uint32_t x0 = (uint32_t)bfc(exp2_hw(s1[nt][0])) |                        \
                    ((uint32_t)bfc(exp2_hw(s1[nt][1])) << 16);                 \
      uint32_t x1 = (uint32_t)bfc(exp2_hw(s1[nt][2])) |                        \
                    ((uint32_t)bfc(exp2_hw(s1[nt][3])) << 16);                 \
      *reinterpret_cast<uint64_t*>(pwA[nt] + 1024) =                           \
          (uint64_t)x0 | ((uint64_t)x1 << 32);                                 \
    }                                                                          \
    {                                                                          \
      bf16x8 pb00 = *reinterpret_cast<const bf16x8*>(pr0);                     \
      bf16x8 pb10 = *reinterpret_cast<const bf16x8*>(pr0 + 1024);              \
      la0 = __builtin_amdgcn_mfma_f32_16x16x32_bf16(ones, pb00, la0, 0, 0, 0); \
      la1 = __builtin_amdgcn_mfma_f32_16x16x32_bf16(ones, pb10, la1, 0, 0, 0); \
      _Pragma("unroll") for (int dt = 0; dt < 4; ++dt) {                       \
        bf16x8 vt = *reinterpret_cast<const bf16x8*>(vt##R##_0 + dt * 1024);   \
        o0[dt] = __builtin_amdgcn_mfma_f32_16x16x32_bf16(vt, pb00, o0[dt], 0, 0, 0); \
        o1[dt] = __builtin_amdgcn_mfma_f32_16x16x32_bf16(vt, pb10, o1[dt], 0, 0, 0); \
      }                                                                        \
      bf16x8 pb01 = *reinterpret_cast<const bf16x8*>(pr1);                     \
      bf16x8 pb11 = *reinterpret_cast<const bf16x8*>(pr1 + 1024);              \
      la0 = __builtin_amdgcn_mfma_f32_16x16x32_bf16(ones, pb01, la0, 0, 0, 0); \
      la1 = __builtin_amdgcn_mfma_f32_16x16x32_bf16(ones, pb11, la1, 0, 0, 0); \
      _Pragma("unroll") for (int dt = 0; dt < 4; ++dt) {                       \
        bf16x8 vt = *reinterpret_cast<const bf16x8*>(vt##R##_1 + dt * 1024);   \
        o0[dt] = __builtin_amdgcn_mfma_f32_16x16x32_bf16(vt, pb01, o0[dt], 0, 0, 0); \
        o1[dt] = __builtin_amdgcn_mfma_f32_16x16x32_bf16(vt, pb11, o1[dt], 0, 0, 0); \
      }                                                                        \
    }                                                                          \
    __syncthreads();                                                           \
  }

  for (int kt = 0; kt < NT; kt += 2) {
    ATTN_TILE(kt, 0, 1)
    ATTN_TILE(kt + 1, 1, 0)
  }
#undef ATTN_TILE

  // la[r] all hold lsum[q=l15] (ones-MFMA replicates across rows)
  const float rn0 = 1.f / la0[0];
  const float rn1 = 1.f / la1[0];
  const int q0r = qt * 128 + wid * 32 + l15;
  u16* crow0 = ctx + (int64_t)(b * SS + q0r) * DMODEL + h * DK;
  u16* crow1 = crow0 + 16 * DMODEL;
  #pragma unroll
  for (int dt = 0; dt < 4; ++dt) {
    s16x4 ov0, ov1;
    #pragma unroll
    for (int r = 0; r < 4; ++r) {
      ov0[r] = (short)bfc(o0[dt][r] * rn0);
      ov1[r] = (short)bfc(o1[dt][r] * rn1);
    }
    *reinterpret_cast<s16x4*>(crow0 + dt * 16 + lg * 4) = ov0;
    *reinterpret_cast<s16x4*>(crow1 + dt * 16 + lg * 4) = ov1;
  }
}

// ---------------- output projection + bias + residual -> preLN (fp32) ------
__global__ __launch_bounds__(256) void out_gemm(
    const u16* __restrict__ ctx, const u16* __restrict__ Wob,
    const float* __restrict__ bo, const float* __restrict__ Qin,
    float* __restrict__ preLN)
{
  __shared__ u16 As[128 * 64], Bs[128 * 64];
  f32x4 acc[4][4] = {};
  gemm128_core(ctx, Wob, blockIdx.x, blockIdx.y, As, Bs, acc);

  const int lane = threadIdx.x & 63, wid = threadIdx.x >> 6;
  const int wr = wid >> 1, wc = wid & 1;
  #pragma unroll
  for (int j = 0; j < 4; ++j) {
    int n = blockIdx.y * 128 + wc * 64 + j * 16 + (lane & 15);
    float bv_ = bo[n];
    #pragma unroll
    for (int i = 0; i < 4; ++i) {
      int mbase = blockIdx.x * 128 + wr * 64 + i * 16 + (lane >> 4) * 4;
      #pragma unroll
      for (int r = 0; r < 4; ++r) {
        int m = mbase + r;
        preLN[(int64_t)m * DMODEL + n] = acc[i][j][r] + bv_ + Qin[(int64_t)m * DMODEL + n];
      }
    }
  }
}

// ---------------- LayerNorm: one wave per 512-elem row ----------------------
__global__ __launch_bounds__(256) void ln_kernel(
    const float* __restrict__ x, const float* __restrict__ gamma,
    const float* __restrict__ beta, float* __restrict__ out)
{
  const int row = blockIdx.x * 4 + (threadIdx.x >> 6);
  const int lane = threadIdx.x & 63;
  const float* xr = x + (int64_t)row * DMODEL;
  const int cbase = lane * 8;
  float4 a = *reinterpret_cast<const float4*>(xr + cbase);
  float4 c = *reinterpret_cast<const float4*>(xr + cbase + 4);
  float s = a.x + a.y + a.z + a.w + c.x + c.y + c.z + c.w;
  float s2 = a.x*a.x + a.y*a.y + a.z*a.z + a.w*a.w +
             c.x*c.x + c.y*c.y + c.z*c.z + c.w*c.w;
  #pragma unroll
  for (int m = 1; m < 64; m <<= 1) { s += __shfl_xor(s, m); s2 += __shfl_xor(s2, m); }
  float mu = s * (1.f / DMODEL);
  float var = s2 * (1.f / DMODEL) - mu * mu;
  float rstd = rsqrtf(var + 1e-5f);
  float4 g0 = *reinterpret_cast<const float4*>(gamma + cbase);
  float4 g1 = *reinterpret_cast<const float4*>(gamma + cbase + 4);
  float4 b0 = *reinterpret_cast<const float4*>(beta + cbase);
  float4 b1 = *reinterpret_cast<const float4*>(beta + cbase + 4);
  float4 o0, o1;
  o0.x = (a.x - mu) * rstd * g0.x + b0.x;
  o0.y = (a.y - mu) * rstd * g0.y + b0.y;
  o0.z = (a.z - mu) * rstd * g0.z + b0.z;
  o0.w = (a.w - mu) * rstd * g0.w + b0.w;
  o1.x = (c.x - mu) * rstd * g1.x + b1.x;
  o1.y = (c.y - mu) * rstd * g1.y + b1.y;
  o1.z = (c.z - mu) * rstd * g1.z + b1.z;
  o1.w = (c.w - mu) * rstd * g1.w + b1.w;
  float* orow = out + (int64_t)row * DMODEL;
  *reinterpret_cast<float4*>(orow + cbase) = o0;
  *reinterpret_cast<float4*>(orow + cbase + 4) = o1;
}

extern "C" void kernel_launch(void* const* d_in, const int* in_sizes, int n_in,
                              void* d_out, int out_size, void* d_ws, size_t ws_size,
                              hipStream_t stream) {
  (void)in_sizes; (void)n_in; (void)out_size; (void)ws_size;
  const float* Q     = (const float*)d_in[0];
  const float* K     = (const float*)d_in[1];
  const float* V     = (const float*)d_in[2];
  const float* Wq    = (const float*)d_in[3];
  const float* bq    = (const float*)d_in[4];
  const float* Wk    = (const float*)d_in[5];
  const float* bk    = (const float*)d_in[6];
  const float* Wv    = (const float*)d_in[7];
  const float* bv    = (const float*)d_in[8];
  const float* Wo    = (const float*)d_in[9];
  const float* bo    = (const float*)d_in[10];
  const float* gamma = (const float*)d_in[11];
  const float* beta  = (const float*)d_in[12];
  float* out = (float*)d_out;

  const int NBIG = MTOT * DMODEL;   // 4194304 elems
  const int NW = DMODEL * DMODEL;   // 262144 elems
  u16* wsp = (u16*)d_ws;
  u16* Qb  = wsp;
  u16* Kb  = Qb + NBIG;
  u16* Vb  = Kb + NBIG;
  u16* Wqb = Vb + NBIG;
  u16* Wkb = Wqb + NW;
  u16* Wvb = Wkb + NW;
  u16* Wob = Wvb + NW;
  u16* qh  = Wob + NW;
  u16* kh  = qh + NBIG;
  u16* vh  = kh + NBIG;
  u16* ctx = vh + NBIG;
  float* preLN = (float*)Qb;  // aliases Qb+Kb (16MB) — dead by out_gemm time

  convert_kernel<<<dim3(2048), 256, 0, stream>>>(Q, K, V, Wq, Wk, Wv, Wo,
                                                 Qb, Kb, Vb, Wqb, Wkb, Wvb, Wob);
  qkv_gemm<<<dim3(64, 4, 3), 256, 0, stream>>>(Qb, Kb, Vb, Wqb, Wkb, Wvb,
                                               bq, bk, bv, qh, kh, vh);
  attn_kernel<<<dim3(512), 256, 0, stream>>>(qh, kh, vh, ctx);
  out_gemm<<<dim3(64, 4), 256, 0, stream>>>(ctx, Wob, bo, Q, preLN);
  ln_kernel<<<dim3(2048), 256, 0, stream>>>(preLN, gamma, beta, out);
}